// Round 1
// baseline (148.832 us; speedup 1.0000x reference)
//
#include <hip/hip_runtime.h>
#include <math.h>

#define T_LEN 16384
#define C_DIM 1024
#define SCAN_ITERS 30

// ---------------------------------------------------------------------------
// K1: q_last[i] = dot(x[T-1,:], W[i,:])  for i in [0, C)
// one wave (64 lanes) per row i; float4 loads (256 float4 per row, 4/lane)
// ---------------------------------------------------------------------------
__global__ void k_qlast(const float* __restrict__ x, const float* __restrict__ W,
                        float* __restrict__ q_last) {
    int wave = (blockIdx.x * blockDim.x + threadIdx.x) >> 6;  // row index i
    int lane = threadIdx.x & 63;
    if (wave >= C_DIM) return;
    const float4* xr = (const float4*)(x + (size_t)(T_LEN - 1) * C_DIM);
    const float4* wr = (const float4*)(W + (size_t)wave * C_DIM);
    float acc = 0.f;
#pragma unroll
    for (int it = 0; it < 4; ++it) {
        int idx = lane + 64 * it;
        float4 a = xr[idx];
        float4 b = wr[idx];
        acc += a.x * b.x + a.y * b.y + a.z * b.z + a.w * b.w;
    }
#pragma unroll
    for (int off = 32; off > 0; off >>= 1) acc += __shfl_down(acc, off, 64);
    if (lane == 0) q_last[wave] = acc;
}

// ---------------------------------------------------------------------------
// K2: w_eff[j] = sum_i q_last[i] * W[C+i][j]
// 64 blocks x 256 threads: blockIdx&3 -> j group (4x256), blockIdx>>2 -> i
// chunk of 64 rows. Coalesced over j; atomicAdd partials (w_eff pre-zeroed).
// ---------------------------------------------------------------------------
__global__ void k_weff(const float* __restrict__ W, const float* __restrict__ q_last,
                       float* __restrict__ w_eff) {
    int j  = (blockIdx.x & 3) * 256 + threadIdx.x;
    int i0 = (blockIdx.x >> 2) * 64;
    const float* Wk = W + (size_t)C_DIM * C_DIM;  // rows C..2C-1
    float acc = 0.f;
#pragma unroll 8
    for (int i = i0; i < i0 + 64; ++i)
        acc += q_last[i] * Wk[(size_t)i * C_DIM + j];
    atomicAdd(&w_eff[j], acc);
}

// ---------------------------------------------------------------------------
// K3: att[t] = scale * dot(x[t], w_eff);  v[t] = dot(x[t], W[2C]).
// One wave per row t; the only kernel that touches all of x (64 MB).
// w_eff and the single W row stay resident in L1/L2.
// ---------------------------------------------------------------------------
__global__ void k_attv(const float* __restrict__ x, const float* __restrict__ W,
                       const float* __restrict__ w_eff,
                       float* __restrict__ att, float* __restrict__ v) {
    int t = (blockIdx.x * blockDim.x + threadIdx.x) >> 6;
    int lane = threadIdx.x & 63;
    if (t >= T_LEN) return;
    const float4* xr = (const float4*)(x + (size_t)t * C_DIM);
    const float4* we = (const float4*)w_eff;
    const float4* wv = (const float4*)(W + (size_t)(2 * C_DIM) * C_DIM);
    float accA = 0.f, accV = 0.f;
#pragma unroll
    for (int it = 0; it < 4; ++it) {
        int idx = lane + 64 * it;
        float4 a = xr[idx];
        float4 e = we[idx];
        float4 b = wv[idx];
        accA += a.x * e.x + a.y * e.y + a.z * e.z + a.w * e.w;
        accV += a.x * b.x + a.y * b.y + a.z * b.z + a.w * b.w;
    }
#pragma unroll
    for (int off = 32; off > 0; off >>= 1) {
        accA += __shfl_down(accA, off, 64);
        accV += __shfl_down(accV, off, 64);
    }
    if (lane == 0) {
        const float scale = (float)(0.001 / 32.0);  // 0.001/sqrt(1024)
        att[t] = (t == T_LEN - 1) ? -INFINITY : accA * scale;
        v[t]   = accV;
    }
}

// ---------------------------------------------------------------------------
// K4: the 30-iteration expanding-window scan + final y = sum p[t]*v[t].
// Single block of 256 threads; windows are tiny (~12..25) but the code is
// generic up to T. Replicates the jax.lax.scan keep/done semantics exactly:
// the iteration where done first triggers still commits its updates; after
// that everything is frozen, so we break at the *top* of the next iteration.
// ---------------------------------------------------------------------------
__global__ void k_scan(const float* __restrict__ att, const float* __restrict__ v,
                       const float* __restrict__ alpha_p, const float* __restrict__ beta_p,
                       float* __restrict__ out) {
    __shared__ float red[8];
    int tid = threadIdx.x, lane = tid & 63, wid = tid >> 6;

    float a = alpha_p[0], b = beta_p[0], k_old = 0.f;
    int   f_start = 0;
    float f_m = 0.f, f_Z = 1.f;

    for (int it = 0; it < SCAN_ITERS; ++it) {
        float kk = 2.0f * (a + b) / a;
        float wf = ceilf(kk);
        int start;
        if (wf >= (float)T_LEN) {
            start = 0;
        } else {
            int win = (int)wf;
            start = T_LEN - win;
            if (start < 0) start = 0;
        }

        // ---- max over window ----
        float m = -INFINITY;
        for (int t = start + tid; t < T_LEN; t += 256) m = fmaxf(m, att[t]);
#pragma unroll
        for (int off = 32; off > 0; off >>= 1) m = fmaxf(m, __shfl_down(m, off, 64));
        if (lane == 0) red[wid] = m;
        __syncthreads();
        m = fmaxf(fmaxf(red[0], red[1]), fmaxf(red[2], red[3]));
        __syncthreads();

        // ---- Z = sum exp(att-m);  bc = sum exp(att-m)*counts ----
        float Z = 0.f, bc = 0.f;
        for (int t = start + tid; t < T_LEN; t += 256) {
            float e = expf(att[t] - m);   // att[T-1] = -inf -> e = 0
            Z  += e;
            bc += e * (float)(T_LEN - 1 - t);
        }
#pragma unroll
        for (int off = 32; off > 0; off >>= 1) {
            Z  += __shfl_down(Z, off, 64);
            bc += __shfl_down(bc, off, 64);
        }
        if (lane == 0) { red[wid] = Z; red[4 + wid] = bc; }
        __syncthreads();
        float Zt  = red[0] + red[1] + red[2] + red[3];
        float bct = red[4] + red[5] + red[6] + red[7];
        __syncthreads();

        float bu = bct / Zt;

        // commit this iteration's state (kept even if done triggers now)
        f_start = start; f_m = m; f_Z = Zt;
        bool done_next = (kk > (float)T_LEN) || (kk < k_old);
        k_old = kk;
        a += 1.0f;
        b += bu;
        if (done_next) break;   // subsequent iterations are frozen no-ops
    }

    // ---- y = sum_{t>=f_start} exp(att[t]-f_m)/f_Z * v[t] ----
    float y = 0.f;
    for (int t = f_start + tid; t < T_LEN; t += 256)
        y += expf(att[t] - f_m) * v[t];
#pragma unroll
    for (int off = 32; off > 0; off >>= 1) y += __shfl_down(y, off, 64);
    if (lane == 0) red[wid] = y;
    __syncthreads();
    if (tid == 0) out[0] = (red[0] + red[1] + red[2] + red[3]) / f_Z;
}

// ---------------------------------------------------------------------------
extern "C" void kernel_launch(void* const* d_in, const int* in_sizes, int n_in,
                              void* d_out, int out_size, void* d_ws, size_t ws_size,
                              hipStream_t stream) {
    const float* x     = (const float*)d_in[0];   // (1, 16384, 1024) f32
    const float* W     = (const float*)d_in[1];   // (2049, 1024) f32
    const float* alpha = (const float*)d_in[2];   // scalar f32
    const float* beta  = (const float*)d_in[3];   // scalar f32

    float* ws     = (float*)d_ws;
    float* q_last = ws;                    // 1024
    float* w_eff  = ws + C_DIM;            // 1024
    float* att    = ws + 2 * C_DIM;        // 16384
    float* v      = ws + 2 * C_DIM + T_LEN;// 16384

    hipMemsetAsync(w_eff, 0, C_DIM * sizeof(float), stream);
    k_qlast<<<C_DIM / 4, 256, 0, stream>>>(x, W, q_last);
    k_weff<<<64, 256, 0, stream>>>(W, q_last, w_eff);
    k_attv<<<T_LEN / 4, 256, 0, stream>>>(x, W, w_eff, att, v);
    k_scan<<<1, 256, 0, stream>>>(att, v, alpha, beta, (float*)d_out);
}